// Round 1
// baseline (482.726 us; speedup 1.0000x reference)
//
#include <hip/hip_runtime.h>
#include <math.h>

#define B 8
#define C 512
#define K 19
#define HW 16384
#define L2E 1.44269504088896340736f

#define CPW 8                    // c-rows per wave
#define SCHUNK 4096              // s elements per block
#define NSC (HW / SCHUNK)        // 4 s-chunks
#define CPB (CPW * 4)            // 32 c per block (4 waves)
#define CG (C / CPB)             // 16 c-groups per batch

// Kernel 1: per-(b,k) softmax stats. stats[row*2] = -max*log2e, stats[row*2+1] = 1/Z
__global__ __launch_bounds__(256)
void softmax_stats_kernel(const float* __restrict__ aux, float* __restrict__ stats) {
    int row = blockIdx.x;                          // 0 .. B*K-1
    const float4* x4 = (const float4*)(aux + (size_t)row * HW);
    int tid = threadIdx.x;

    // pass 1: max
    float m = -INFINITY;
    for (int i = tid; i < HW / 4; i += 256) {
        float4 v = x4[i];
        m = fmaxf(m, fmaxf(fmaxf(v.x, v.y), fmaxf(v.z, v.w)));
    }
    #pragma unroll
    for (int off = 32; off > 0; off >>= 1) m = fmaxf(m, __shfl_xor(m, off, 64));
    __shared__ float red[4];
    if ((tid & 63) == 0) red[tid >> 6] = m;
    __syncthreads();
    m = fmaxf(fmaxf(red[0], red[1]), fmaxf(red[2], red[3]));
    __syncthreads();   // red reused below

    // pass 2: sum of exp
    float ssum = 0.f;
    for (int i = tid; i < HW / 4; i += 256) {
        float4 v = x4[i];
        ssum += exp2f((v.x - m) * L2E);
        ssum += exp2f((v.y - m) * L2E);
        ssum += exp2f((v.z - m) * L2E);
        ssum += exp2f((v.w - m) * L2E);
    }
    #pragma unroll
    for (int off = 32; off > 0; off >>= 1) ssum += __shfl_xor(ssum, off, 64);
    if ((tid & 63) == 0) red[tid >> 6] = ssum;
    __syncthreads();
    if (tid == 0) {
        float Z = red[0] + red[1] + red[2] + red[3];
        stats[row * 2]     = -m * L2E;
        stats[row * 2 + 1] = 1.0f / Z;
    }
}

// Kernel 2: out[b,c,k] += sum_s p[b,k,s] * feats[b,c,s] over this block's s-chunk.
// Each wave: CPW c-rows, lanes span s (coalesced), probs recomputed on the fly.
__global__ __launch_bounds__(256, 2)
void gather_kernel(const float* __restrict__ feats, const float* __restrict__ aux,
                   const float* __restrict__ stats, float* __restrict__ out) {
    int bid  = blockIdx.x;                 // 0 .. B*CG*NSC-1 (=512)
    int sc   = bid & (NSC - 1);
    int cg   = (bid / NSC) & (CG - 1);
    int b    = bid / (NSC * CG);
    int lane = threadIdx.x & 63;
    int wave = threadIdx.x >> 6;
    int c0   = cg * CPB + wave * CPW;

    const float* Abase = aux   + (size_t)b * K * HW;
    const float* Fbase = feats + ((size_t)b * C + c0) * HW;
    const float* S     = stats + (size_t)b * K * 2;   // wave-uniform -> SGPRs

    float negml[K], invz[K];
    #pragma unroll
    for (int k = 0; k < K; k++) { negml[k] = S[2 * k]; invz[k] = S[2 * k + 1]; }

    float acc[CPW][K];
    #pragma unroll
    for (int c = 0; c < CPW; c++)
        #pragma unroll
        for (int k = 0; k < K; k++) acc[c][k] = 0.f;

    int s0 = sc * SCHUNK + lane;
    for (int step = 0; step < SCHUNK / 64; step++) {
        int s = s0 + step * 64;
        float p[K];
        #pragma unroll
        for (int k = 0; k < K; k++) {
            float a = Abase[(size_t)k * HW + s];
            p[k] = exp2f(fmaf(a, L2E, negml[k])) * invz[k];
        }
        #pragma unroll
        for (int c = 0; c < CPW; c++) {
            float f = Fbase[(size_t)c * HW + s];
            #pragma unroll
            for (int k = 0; k < K; k++) acc[c][k] = fmaf(p[k], f, acc[c][k]);
        }
    }

    // butterfly reduce over the 64 lanes (each lane held a disjoint s-subset)
    #pragma unroll
    for (int c = 0; c < CPW; c++)
        #pragma unroll
        for (int k = 0; k < K; k++) {
            float v = acc[c][k];
            #pragma unroll
            for (int off = 32; off > 0; off >>= 1) v += __shfl_xor(v, off, 64);
            acc[c][k] = v;
        }

    if (lane == 0) {
        #pragma unroll
        for (int c = 0; c < CPW; c++)
            #pragma unroll
            for (int k = 0; k < K; k++)
                atomicAdd(&out[((size_t)b * C + c0 + c) * K + k], acc[c][k]);
    }
}

extern "C" void kernel_launch(void* const* d_in, const int* in_sizes, int n_in,
                              void* d_out, int out_size, void* d_ws, size_t ws_size,
                              hipStream_t stream) {
    const float* feats = (const float*)d_in[0];   // bb_feats [8,512,128,128]
    const float* aux   = (const float*)d_in[1];   // aux_out  [8,19,128,128]
    float* out   = (float*)d_out;                 // [8,512,19,1]
    float* stats = (float*)d_ws;                  // 152 * 2 floats

    hipMemsetAsync(d_out, 0, (size_t)out_size * sizeof(float), stream);
    softmax_stats_kernel<<<B * K, 256, 0, stream>>>(aux, stats);
    gather_kernel<<<B * CG * NSC, 256, 0, stream>>>(feats, aux, stats, out);
}